// Round 3
// baseline (607.874 us; speedup 1.0000x reference)
//
#include <hip/hip_runtime.h>
#include <stdint.h>

// LossRecovery via Gram-matrix collapse (validated round 1):
//   G1 = X^T X, GS = sum_s x_s x_swap(s)^T (symmetric).
//   logits1 = Wq G1 Wk^T + rank1;  W1 = I + gs*attn1*Wv;  x1 = X W1^T + b1eff (never materialized)
//   logits2 = Wtq (W1 GS + b1eff u^T) Wtk^T + rank1
//   out = gather(v2)·(gt*attn2) + X W1^T + b1eff
// Split-bf16 (hi/lo, 3-pass MFMA) on all logit-path GEMMs.
// Round 2: gram = 512 blocks + b64-packed staging + XCD grouping; whole small chain in one k_mega.

#define S4 4096
#define CH 256

typedef __attribute__((ext_vector_type(8))) short bf16x8;
typedef __attribute__((ext_vector_type(4))) float f32x4;

static __device__ __forceinline__ float bf2f(unsigned short u){
  union { unsigned int i; float f; } v; v.i = ((unsigned int)u) << 16; return v.f;
}
static __device__ __forceinline__ unsigned short f2bf(float f){
  union { float f; unsigned int i; } v; v.f = f;
  unsigned int x = v.i;
  x += 0x7fffu + ((x >> 16) & 1u);   // RNE
  return (unsigned short)(x >> 16);
}
static __device__ __forceinline__ void gload16(const void* g, void* l){
  __builtin_amdgcn_global_load_lds((const __attribute__((address_space(1))) void*)g,
                                   (__attribute__((address_space(3))) void*)l, 16, 0, 0);
}

// ---------------- prep ----------------

// block = (bl*64 + chunk): 64 rows; also accumulates column partial sums for u.
__global__ void k_xprep2(const float* __restrict__ x,
                         unsigned short* __restrict__ xhi,
                         unsigned short* __restrict__ xlo,
                         float* __restrict__ ups){
  int blk = blockIdx.x;            // 0..1023
  int c   = threadIdx.x;           // 0..255
  long rbase = (long)blk * 64;
  float s = 0.f;
  for (int i = 0; i < 64; ++i){
    long row = rbase + i;
    float v = x[row*259 + c];
    unsigned short h = f2bf(v);
    xhi[row*256 + c] = h;
    xlo[row*256 + c] = f2bf(v - bf2f(h));
    s += v;
  }
  ups[(long)blk*256 + c] = s;
}

__global__ void k_vecfin(const float* __restrict__ ups, float* __restrict__ u){
  int bl = blockIdx.x, e = threadIdx.x;
  float s = 0.f;
  for (int ch = 0; ch < 64; ++ch) s += ups[(long)(bl*64 + ch)*256 + e];
  u[bl*256 + e] = s;
}

__global__ void k_wprep(const float* __restrict__ w0, const float* __restrict__ w1,
                        const float* __restrict__ w2, const float* __restrict__ w3,
                        const float* __restrict__ w4, const float* __restrict__ w5,
                        unsigned short* __restrict__ whi, unsigned short* __restrict__ wlo,
                        unsigned short* __restrict__ wvthi, unsigned short* __restrict__ wvtlo){
  int i = blockIdx.x*256 + threadIdx.x;   // 0 .. 7*65536
  int mat = i >> 16; int off = i & 65535;
  if (mat < 6){
    const float* src = mat==0?w0:mat==1?w1:mat==2?w2:mat==3?w3:mat==4?w4:w5;
    float v = src[off];
    unsigned short h = f2bf(v);
    whi[i] = h;
    wlo[i] = f2bf(v - bf2f(h));
  } else {
    int e = off >> 8, d = off & 255;
    float v = w2[d*256 + e];              // WvT[e][d] = sv_w[d][e]
    unsigned short h = f2bf(v);
    wvthi[off] = h;
    wvtlo[off] = f2bf(v - bf2f(h));
  }
}

// combine 8 Gram partials -> hi/lo
__global__ void k_gcomb(const float* __restrict__ Gp,
                        unsigned short* __restrict__ ghi, unsigned short* __restrict__ glo){
  int bl = blockIdx.y;
  int idx = blockIdx.x*256 + threadIdx.x;
  float s = 0.f;
  #pragma unroll
  for (int p = 0; p < 8; ++p) s += Gp[(long)(bl*8 + p)*65536 + idx];
  unsigned short h = f2bf(s);
  ghi[(long)bl*65536 + idx] = h;
  glo[(long)bl*65536 + idx] = f2bf(s - bf2f(h));
}

// ---------------- Gram kernel: C[e][f] = sum_s X[s][e] * Xsw[s][f], 3-pass split ----------------
// 512 blocks: lg = xcd-grouped remap; zz = bl*8+sp (split-K 8), tiles 2x2.

template<bool BSWAP>
__global__ __launch_bounds__(256) void k_gram(
  const unsigned short* __restrict__ Xhi, const unsigned short* __restrict__ Xlo,
  float* __restrict__ Gp)
{
  __shared__ char lds[65536];
  char* ldsAh = lds;
  char* ldsAl = lds + 16384;
  char* ldsBh = lds + 32768;
  char* ldsBl = lds + 49152;

  const int tid = threadIdx.x;
  const int l = tid & 63, wid = tid >> 6;
  const int wm = wid >> 1, wn = wid & 1;
  const int lm = l & 15, lk = l >> 4;
  const int fm = wm*64, fn = wn*64;

  int flat = blockIdx.x + 2*(blockIdx.y + 2*blockIdx.z);     // hw linear id
  int lg = (flat & 7)*64 + (flat >> 3);                      // same-xcd groups of 64
  const int m0 = (lg & 1)*128;
  const int n0 = ((lg >> 1) & 1)*128;
  const int zz = lg >> 2;                                    // 0..127
  const int bl = zz >> 3, sp = zz & 7;
  const long Xoff = (long)bl * (4096*256);

  const int sg = tid & 15;        // s-group of 4
  const int eg = tid >> 4;        // e-group of 8

  f32x4 acc[4][4];
  #pragma unroll
  for (int i=0;i<4;++i)
    #pragma unroll
    for (int j=0;j<4;++j) acc[i][j] = (f32x4){0.f,0.f,0.f,0.f};

  union U4 { int4 v; unsigned short u[8]; };

  for (int kt = 0; kt < 8; ++kt){
    const int k0 = sp*512 + kt*64;
    U4 va[4], vla[4], vb[4], vlb[4];
    #pragma unroll
    for (int ss = 0; ss < 4; ++ss){
      int sa = k0 + sg*4 + ss;
      int sb = BSWAP ? (((sa & 63) << 6) | (sa >> 6)) : sa;
      long gaA = Xoff + (long)sa*256 + m0 + eg*8;
      long gaB = Xoff + (long)sb*256 + n0 + eg*8;
      va[ss].v  = *(const int4*)(Xhi + gaA);
      vla[ss].v = *(const int4*)(Xlo + gaA);
      vb[ss].v  = *(const int4*)(Xhi + gaB);
      vlb[ss].v = *(const int4*)(Xlo + gaB);
    }
    #pragma unroll
    for (int j = 0; j < 8; ++j){
      int e_loc = eg*8 + j;
      int bo = e_loc*128 + ((sg*8) ^ (j << 4));
      ushort4 t;
      t.x=va[0].u[j];  t.y=va[1].u[j];  t.z=va[2].u[j];  t.w=va[3].u[j];
      *(ushort4*)(ldsAh + bo) = t;
      t.x=vla[0].u[j]; t.y=vla[1].u[j]; t.z=vla[2].u[j]; t.w=vla[3].u[j];
      *(ushort4*)(ldsAl + bo) = t;
      t.x=vb[0].u[j];  t.y=vb[1].u[j];  t.z=vb[2].u[j];  t.w=vb[3].u[j];
      *(ushort4*)(ldsBh + bo) = t;
      t.x=vlb[0].u[j]; t.y=vlb[1].u[j]; t.z=vlb[2].u[j]; t.w=vlb[3].u[j];
      *(ushort4*)(ldsBl + bo) = t;
    }
    __syncthreads();
    #pragma unroll
    for (int kk = 0; kk < 2; ++kk){
      bf16x8 ah[4], al_[4];
      #pragma unroll
      for (int i=0;i<4;++i){
        int r = fm + i*16 + lm;
        int kb = ((kk<<6) + (lk<<4)) ^ ((r & 7) << 4);
        ah[i]  = *(const bf16x8*)(ldsAh + r*128 + kb);
        al_[i] = *(const bf16x8*)(ldsAl + r*128 + kb);
      }
      #pragma unroll
      for (int j=0;j<4;++j){
        int r = fn + j*16 + lm;
        int kb = ((kk<<6) + (lk<<4)) ^ ((r & 7) << 4);
        bf16x8 bh  = *(const bf16x8*)(ldsBh + r*128 + kb);
        bf16x8 bl8 = *(const bf16x8*)(ldsBl + r*128 + kb);
        #pragma unroll
        for (int i=0;i<4;++i){
          acc[i][j] = __builtin_amdgcn_mfma_f32_16x16x32_bf16(ah[i], bh, acc[i][j], 0, 0, 0);
          acc[i][j] = __builtin_amdgcn_mfma_f32_16x16x32_bf16(ah[i], bl8, acc[i][j], 0, 0, 0);
          acc[i][j] = __builtin_amdgcn_mfma_f32_16x16x32_bf16(al_[i], bh, acc[i][j], 0, 0, 0);
        }
      }
    }
    __syncthreads();
  }

  float* ldsF = (float*)lds;
  #pragma unroll
  for (int chv = 0; chv < 4; ++chv){
    __syncthreads();
    if (wm == (chv >> 1)){
      #pragma unroll
      for (int i2=0;i2<2;++i2){
        int i = (chv & 1)*2 + i2;
        #pragma unroll
        for (int j=0;j<4;++j){
          int n = fn + j*16 + lm;
          int m2 = i2*16 + lk*4;
          #pragma unroll
          for (int r2=0;r2<4;++r2) ldsF[(m2+r2)*136 + n] = acc[i][j][r2];
        }
      }
    }
    __syncthreads();
    #pragma unroll
    for (int g2 = 0; g2 < 2; ++g2){
      int t2 = g2*256 + tid;
      int rr = t2 >> 4;
      int co = (t2 & 15) * 8;
      int mg = m0 + chv*32 + rr;
      int ng = n0 + co;
      long oidx = (long)zz*65536 + (long)mg*256 + ng;
      float4 o0, o1;
      o0.x = ldsF[rr*136+co+0]; o0.y = ldsF[rr*136+co+1];
      o0.z = ldsF[rr*136+co+2]; o0.w = ldsF[rr*136+co+3];
      o1.x = ldsF[rr*136+co+4]; o1.y = ldsF[rr*136+co+5];
      o1.z = ldsF[rr*136+co+6]; o1.w = ldsF[rr*136+co+7];
      *(float4*)(Gp + oidx)     = o0;
      *(float4*)(Gp + oidx + 4) = o1;
    }
  }
}

// ---------------- mega kernel: whole per-frame small-matrix chain ----------------
// 512 threads = 2 groups x 4 waves; per stage: C[m][n] = sum_k (Ah+Al)[m][k]*(Bh+Bl)[n][k], K=256.

__device__ __forceinline__ void mega_tile(
  char* lds, int tid,
  const unsigned short* __restrict__ Ah, const unsigned short* __restrict__ Al,
  const unsigned short* __restrict__ Bh, const unsigned short* __restrict__ Bl,
  f32x4 acc[4][4])
{
  char* ldsAh = lds;
  char* ldsAl = lds + 32768;
  char* ldsBh = lds + 65536;
  char* ldsBl = lds + 81920;
  const int l = tid & 63, wid = tid >> 6;
  const int g = wid >> 2, w2 = wid & 3;
  const int wm = w2 >> 1, wn = w2 & 1;
  const int lm = l & 15, lk = l >> 4;
  const int fm = g*128 + wm*64, fn = wn*64;

  for (int kt = 0; kt < 4; ++kt){
    const int kq = kt << 6;
    #pragma unroll
    for (int it = 0; it < 4; ++it){      // A: 256 rows x 64 k
      int idx = it*512 + tid;            // 0..2047
      int r = idx >> 3;
      int kb = ((idx & 7) << 4) ^ ((r & 7) << 4);
      long ga = (long)r*256 + kq + (kb >> 1);
      gload16(Ah + ga, ldsAh + idx*16);
      gload16(Al + ga, ldsAl + idx*16);
    }
    #pragma unroll
    for (int it = 0; it < 2; ++it){      // B: 128 rows x 64 k
      int idx = it*512 + tid;            // 0..1023
      int r = idx >> 3;
      int kb = ((idx & 7) << 4) ^ ((r & 7) << 4);
      long gb = (long)r*256 + kq + (kb >> 1);
      gload16(Bh + gb, ldsBh + idx*16);
      gload16(Bl + gb, ldsBl + idx*16);
    }
    __syncthreads();
    #pragma unroll
    for (int kk = 0; kk < 2; ++kk){
      bf16x8 ah[4], al_[4];
      #pragma unroll
      for (int i=0;i<4;++i){
        int r = fm + i*16 + lm;          // 0..255
        int kb = ((kk<<6) + (lk<<4)) ^ ((r & 7) << 4);
        ah[i]  = *(const bf16x8*)(ldsAh + r*128 + kb);
        al_[i] = *(const bf16x8*)(ldsAl + r*128 + kb);
      }
      #pragma unroll
      for (int j=0;j<4;++j){
        int r = fn + j*16 + lm;          // 0..127
        int kb = ((kk<<6) + (lk<<4)) ^ ((r & 7) << 4);
        bf16x8 bh  = *(const bf16x8*)(ldsBh + r*128 + kb);
        bf16x8 bl8 = *(const bf16x8*)(ldsBl + r*128 + kb);
        #pragma unroll
        for (int i=0;i<4;++i){
          acc[i][j] = __builtin_amdgcn_mfma_f32_16x16x32_bf16(ah[i], bh, acc[i][j], 0, 0, 0);
          acc[i][j] = __builtin_amdgcn_mfma_f32_16x16x32_bf16(ah[i], bl8, acc[i][j], 0, 0, 0);
          acc[i][j] = __builtin_amdgcn_mfma_f32_16x16x32_bf16(al_[i], bh, acc[i][j], 0, 0, 0);
        }
      }
    }
    __syncthreads();
  }
}

// MODE: 0 = bf16 hi/lo; 1 = fp32 + 2 rank1; 2 = W1 (I + gs*v, hi/lo, h1-accum); 3 = rank1 + hi/lo
template<int MODE>
__device__ __forceinline__ void mega_epi(
  char* lds, int tid, f32x4 acc[4][4], int bl, int n0, float gs,
  const float* ra1, const float* rb1, const float* ra2, const float* rb2,
  const float* pu, float* ph1,
  unsigned short* __restrict__ Oh, unsigned short* __restrict__ Ol,
  float* __restrict__ O32)
{
  const int l = tid & 63, wid = tid >> 6;
  const int g = wid >> 2, w2 = wid & 3;
  const int wm = w2 >> 1, wn = w2 & 1;
  const int lm = l & 15, lk = l >> 4;
  const int fnl = wn*64;
  float* ldsF = (float*)(lds + g*17408);
  const int tid2 = tid & 255;
  const int gr = tid >> 8;                // readout group (== wave group)

  #pragma unroll
  for (int chv = 0; chv < 4; ++chv){
    __syncthreads();
    if (wm == (chv >> 1)){
      #pragma unroll
      for (int i2=0;i2<2;++i2){
        int i = (chv & 1)*2 + i2;
        #pragma unroll
        for (int j=0;j<4;++j){
          int n = fnl + j*16 + lm;
          int m2 = i2*16 + lk*4;
          #pragma unroll
          for (int r2=0;r2<4;++r2) ldsF[(m2+r2)*136 + n] = acc[i][j][r2];
        }
      }
    }
    __syncthreads();
    float* ldsFr = (float*)(lds + gr*17408);
    #pragma unroll
    for (int g2 = 0; g2 < 2; ++g2){
      int t2 = g2*256 + tid2;
      int rr = t2 >> 4;
      int co = (t2 & 15) * 8;
      float v[8];
      #pragma unroll
      for (int e=0;e<8;++e) v[e] = ldsFr[rr*136 + co + e];
      int mg = gr*128 + chv*32 + rr;
      int ng = n0 + co;
      long oidx = (long)bl*65536 + (long)mg*256 + ng;
      if (MODE == 1){
        float a1v = ra1[mg], a2v = ra2[mg];
        #pragma unroll
        for (int e=0;e<8;++e) v[e] += a1v*rb1[ng+e] + a2v*rb2[ng+e];
        float4 o0, o1;
        o0.x=v[0]; o0.y=v[1]; o0.z=v[2]; o0.w=v[3];
        o1.x=v[4]; o1.y=v[5]; o1.z=v[6]; o1.w=v[7];
        *(float4*)(O32 + oidx)     = o0;
        *(float4*)(O32 + oidx + 4) = o1;
      } else {
        if (MODE == 2){
          float hs = 0.f;
          #pragma unroll
          for (int e=0;e<8;++e){
            float w = ((mg == ng + e) ? 1.f : 0.f) + gs*v[e];
            hs += w * pu[ng+e];
            v[e] = w;
          }
          atomicAdd(&ph1[mg], hs);
        }
        if (MODE == 3){
          float a1v = ra1[mg];
          #pragma unroll
          for (int e=0;e<8;++e) v[e] += a1v * rb1[ng+e];
        }
        union { int4 vv; unsigned short u[8]; } hh, ll;
        #pragma unroll
        for (int e=0;e<8;++e) hh.u[e] = f2bf(v[e]);
        *(int4*)(Oh + oidx) = hh.vv;
        #pragma unroll
        for (int e=0;e<8;++e) ll.u[e] = f2bf(v[e] - bf2f(hh.u[e]));
        *(int4*)(Ol + oidx) = ll.vv;
      }
    }
  }
  __threadfence();
  __syncthreads();
}

// SMODE 0: a1 hi/lo + c1 accumulation.  SMODE 1: a2 = tg*p, hi only.
template<int SMODE>
__device__ __forceinline__ void mega_softmax(
  int bl, int tid, const float* __restrict__ logits, float tg,
  const float* psvb, float* pc1,
  unsigned short* __restrict__ Oh, unsigned short* __restrict__ Ol)
{
  const int l = tid & 63, wid = tid >> 6;
  const long base = (long)bl*65536;
  for (int rr = 0; rr < 32; rr += 2){
    int c0 = wid*32 + rr;
    const float* p0 = logits + base + (long)c0*256 + l*4;
    float4 va = *(const float4*)p0;
    float4 vb = *(const float4*)(p0 + 256);
    float ma = fmaxf(fmaxf(va.x,va.y), fmaxf(va.z,va.w));
    float mb = fmaxf(fmaxf(vb.x,vb.y), fmaxf(vb.z,vb.w));
    #pragma unroll
    for (int off=32; off; off>>=1){
      ma = fmaxf(ma, __shfl_xor(ma, off, 64));
      mb = fmaxf(mb, __shfl_xor(mb, off, 64));
    }
    float ea0=__expf(va.x-ma), ea1=__expf(va.y-ma), ea2=__expf(va.z-ma), ea3=__expf(va.w-ma);
    float eb0=__expf(vb.x-mb), eb1=__expf(vb.y-mb), eb2=__expf(vb.z-mb), eb3=__expf(vb.w-mb);
    float sa = ea0+ea1+ea2+ea3, sb = eb0+eb1+eb2+eb3;
    float da = 0.f, db = 0.f;
    if (SMODE == 0){
      float4 bv = *(const float4*)(psvb + l*4);
      da = ea0*bv.x + ea1*bv.y + ea2*bv.z + ea3*bv.w;
      db = eb0*bv.x + eb1*bv.y + eb2*bv.z + eb3*bv.w;
    }
    #pragma unroll
    for (int off=32; off; off>>=1){
      sa += __shfl_xor(sa, off, 64);
      sb += __shfl_xor(sb, off, 64);
      if (SMODE == 0){ da += __shfl_xor(da, off, 64); db += __shfl_xor(db, off, 64); }
    }
    float ia = 1.f/sa, ib = 1.f/sb;
    if (SMODE == 1){ ia *= tg; ib *= tg; }
    float pa0=ea0*ia, pa1=ea1*ia, pa2=ea2*ia, pa3=ea3*ia;
    float pb0=eb0*ib, pb1v=eb1*ib, pb2=eb2*ib, pb3=eb3*ib;
    ushort4 h0, h1v;
    h0.x=f2bf(pa0); h0.y=f2bf(pa1); h0.z=f2bf(pa2); h0.w=f2bf(pa3);
    h1v.x=f2bf(pb0); h1v.y=f2bf(pb1v); h1v.z=f2bf(pb2); h1v.w=f2bf(pb3);
    *(ushort4*)(Oh + base + (long)c0*256 + l*4)     = h0;
    *(ushort4*)(Oh + base + (long)(c0+1)*256 + l*4) = h1v;
    if (SMODE == 0){
      ushort4 l0, l1v;
      l0.x=f2bf(pa0-bf2f(h0.x)); l0.y=f2bf(pa1-bf2f(h0.y));
      l0.z=f2bf(pa2-bf2f(h0.z)); l0.w=f2bf(pa3-bf2f(h0.w));
      l1v.x=f2bf(pb0-bf2f(h1v.x)); l1v.y=f2bf(pb1v-bf2f(h1v.y));
      l1v.z=f2bf(pb2-bf2f(h1v.z)); l1v.w=f2bf(pb3-bf2f(h1v.w));
      *(ushort4*)(Ol + base + (long)c0*256 + l*4)     = l0;
      *(ushort4*)(Ol + base + (long)(c0+1)*256 + l*4) = l1v;
      if (l == 0){ pc1[c0] = da*ia; pc1[c0+1] = db*ib; }
    }
  }
}

__global__ __launch_bounds__(512) void k_mega(
  const unsigned short* __restrict__ Whi, const unsigned short* __restrict__ Wlo,
  const unsigned short* __restrict__ WvThi, const unsigned short* __restrict__ WvTlo,
  const unsigned short* __restrict__ G1hi, const unsigned short* __restrict__ G1lo,
  const unsigned short* __restrict__ GShi, const unsigned short* __restrict__ GSlo,
  const float* __restrict__ sq_w, const float* __restrict__ sk_w,
  const float* __restrict__ tk_w, const float* __restrict__ tq_w,
  const float* __restrict__ sq_b, const float* __restrict__ sk_b,
  const float* __restrict__ sv_b, const float* __restrict__ tq_b,
  const float* __restrict__ tk_b,
  const float* __restrict__ s_gp, const float* __restrict__ t_gp,
  const float* __restrict__ u,
  unsigned short* __restrict__ Pth, unsigned short* __restrict__ Ptl,
  float* __restrict__ logits,
  unsigned short* __restrict__ a1h, unsigned short* __restrict__ a1l,
  unsigned short* __restrict__ W1h, unsigned short* __restrict__ W1l,
  unsigned short* __restrict__ G2h, unsigned short* __restrict__ G2l,
  unsigned short* __restrict__ a2g,
  float* __restrict__ b1eff_g)
{
  __shared__ char lds[111616];
  float* P = (float*)(lds + 98304);
  float* pu    = P;
  float* psqb  = P + 256;
  float* pskb  = P + 512;
  float* psvb  = P + 768;
  float* ptqb  = P + 1024;
  float* ptkb  = P + 1280;
  float* pwqu  = P + 1536;
  float* pwku  = P + 1792;
  float* pwtku = P + 2048;
  float* pwtqh = P + 2304;
  float* pc1   = P + 2560;
  float* ph1   = P + 2816;
  float* pb1   = P + 3072;

  const int tid = threadIdx.x;
  const int bl = blockIdx.x;
  const float gs = s_gp[0], tg = t_gp[0];
  const long gb = (long)bl*65536;

  if (tid < 256){
    pu[tid]   = u[bl*256 + tid];
    psqb[tid] = sq_b[tid];
    pskb[tid] = sk_b[tid];
    psvb[tid] = sv_b[tid];
    ptqb[tid] = tq_b[tid];
    ptkb[tid] = tk_b[tid];
    ph1[tid]  = 0.f;
  }
  __syncthreads();

  // S0: matvecs wqu/wtku (half 0), wku (half 1)
  {
    int c = tid & 255, hh = tid >> 8;
    if (hh == 0){
      float s1 = 0.f, s2 = 0.f;
      #pragma unroll 4
      for (int e = 0; e < 256; e += 4){
        float4 w1_ = *(const float4*)(sq_w + c*256 + e);
        float4 w2_ = *(const float4*)(tk_w + c*256 + e);
        float u0=pu[e], u1=pu[e+1], u2=pu[e+2], u3=pu[e+3];
        s1 += w1_.x*u0 + w1_.y*u1 + w1_.z*u2 + w1_.w*u3;
        s2 += w2_.x*u0 + w2_.y*u1 + w2_.z*u2 + w2_.w*u3;
      }
      pwqu[c]  = s1 + 4096.f*psqb[c];
      pwtku[c] = s2;
    } else {
      float s = 0.f;
      #pragma unroll 4
      for (int e = 0; e < 256; e += 4){
        float4 w1_ = *(const float4*)(sk_w + c*256 + e);
        s += w1_.x*pu[e] + w1_.y*pu[e+1] + w1_.z*pu[e+2] + w1_.w*pu[e+3];
      }
      pwku[c] = s;
    }
    __syncthreads();
  }

  f32x4 acc[4][4];
  #define ZACC { for (int i_=0;i_<4;++i_) for (int j_=0;j_<4;++j_) acc[i_][j_]=(f32x4){0.f,0.f,0.f,0.f}; }

  // S1: Pt1 = Wk x G1
  for (int n0 = 0; n0 < 256; n0 += 128){
    ZACC;
    mega_tile(lds, tid, Whi + 65536, Wlo + 65536, G1hi + gb + n0*256, G1lo + gb + n0*256, acc);
    mega_epi<0>(lds, tid, acc, bl, n0, 0.f, nullptr,nullptr,nullptr,nullptr, pu, ph1, Pth, Ptl, nullptr);
  }
  // S2: L1 = Wq x Pt1 + wqu*bk + bq*wku
  for (int n0 = 0; n0 < 256; n0 += 128){
    ZACC;
    mega_tile(lds, tid, Whi, Wlo, Pth + gb + n0*256, Ptl + gb + n0*256, acc);
    mega_epi<1>(lds, tid, acc, bl, n0, 0.f, pwqu, pskb, psqb, pwku, pu, ph1, nullptr, nullptr, logits);
  }
  // S3: softmax1 -> a1 hi/lo, c1
  mega_softmax<0>(bl, tid, logits, 1.f, psvb, pc1, a1h, a1l);
  __threadfence();
  __syncthreads();
  // S4: M1 = a1 x WvT ; W1 = I + gs*M1 ; ph1[c] = sum_e W1[c,e]*u[e]
  for (int n0 = 0; n0 < 256; n0 += 128){
    ZACC;
    mega_tile(lds, tid, a1h + gb, a1l + gb, WvThi + n0*256, WvTlo + n0*256, acc);
    mega_epi<2>(lds, tid, acc, bl, n0, gs, nullptr,nullptr,nullptr,nullptr, pu, ph1, W1h, W1l, nullptr);
  }
  // S5: b1eff, h1, wtqh
  if (tid < 256){
    float b1 = gs * pc1[tid];
    pb1[tid] = b1;
    b1eff_g[bl*256 + tid] = b1;
    ph1[tid] = ph1[tid] + 4096.f*b1;
  }
  __syncthreads();
  if (tid < 256){
    int c = tid;
    float s = 0.f;
    #pragma unroll 4
    for (int e = 0; e < 256; e += 4){
      float4 w = *(const float4*)(tq_w + c*256 + e);
      s += w.x*ph1[e] + w.y*ph1[e+1] + w.z*ph1[e+2] + w.w*ph1[e+3];
    }
    pwtqh[c] = s + 4096.f*ptqb[c];
  }
  __syncthreads();
  // S6: G2 = W1 x GS + b1*u^T
  for (int n0 = 0; n0 < 256; n0 += 128){
    ZACC;
    mega_tile(lds, tid, W1h + gb, W1l + gb, GShi + gb + n0*256, GSlo + gb + n0*256, acc);
    mega_epi<3>(lds, tid, acc, bl, n0, 0.f, pb1, pu, nullptr, nullptr, pu, ph1, G2h, G2l, nullptr);
  }
  // S7: Pt2 = Wtk x G2
  for (int n0 = 0; n0 < 256; n0 += 128){
    ZACC;
    mega_tile(lds, tid, Whi + 4*65536, Wlo + 4*65536, G2h + gb + n0*256, G2l + gb + n0*256, acc);
    mega_epi<0>(lds, tid, acc, bl, n0, 0.f, nullptr,nullptr,nullptr,nullptr, pu, ph1, Pth, Ptl, nullptr);
  }
  // S8: L2 = Wtq x Pt2 + wtqh*btk + btq*wtku
  for (int n0 = 0; n0 < 256; n0 += 128){
    ZACC;
    mega_tile(lds, tid, Whi + 3*65536, Wlo + 3*65536, Pth + gb + n0*256, Ptl + gb + n0*256, acc);
    mega_epi<1>(lds, tid, acc, bl, n0, 0.f, pwtqh, ptkb, ptqb, pwtku, pu, ph1, nullptr, nullptr, logits);
  }
  // S9: softmax2 (x tg) -> a2g
  mega_softmax<1>(bl, tid, logits, tg, psvb, pc1, a2g, nullptr);
  #undef ZACC
}

// ---------------- generic K=256 GEMM (kept for v2 conv; validated round 1) ----------------

template<bool SPLIT,int OUT_MODE>
__global__ __launch_bounds__(256) void k_gemm(
  const unsigned short* __restrict__ Ahi, const unsigned short* __restrict__ Alo,
  long Abl, int Ars,
  const unsigned short* __restrict__ Bhi, const unsigned short* __restrict__ Blo,
  long Bbl, int Brs,
  const float* __restrict__ bias,
  unsigned short* __restrict__ O16a,
  long Obl, int Ors)
{
  constexpr int LDSZ = 32768;
  __shared__ char lds[LDSZ];
  char* ldsAh = lds;
  char* ldsBh = lds + 16384;

  const int tid = threadIdx.x;
  const int l   = tid & 63;
  const int wid = tid >> 6;
  const int wm  = wid >> 1, wn = wid & 1;
  const int lm  = l & 15, lk = l >> 4;
  const int fm  = wm*64, fn = wn*64;
  const int bl  = blockIdx.z;
  const int m0  = blockIdx.x * 128;
  const int n0  = blockIdx.y * 128;

  f32x4 acc[4][4];
  #pragma unroll
  for (int i=0;i<4;++i)
    #pragma unroll
    for (int j=0;j<4;++j) acc[i][j] = (f32x4){0.f,0.f,0.f,0.f};

  for (int kt = 0; kt < 4; ++kt){
    const int kq = kt << 6;
    #pragma unroll
    for (int it=0; it<4; ++it){
      int idx = it*256 + tid;
      int r = idx >> 3;
      int kb = ((idx & 7) << 4) ^ ((r & 7) << 4);
      long ga = (long)bl*Abl + (long)(m0 + r)*Ars + kq + (kb >> 1);
      gload16(Ahi + ga, ldsAh + idx*16);
      long gbb = (long)bl*Bbl + (long)(n0 + r)*Brs + kq + (kb >> 1);
      gload16(Bhi + gbb, ldsBh + idx*16);
    }
    __syncthreads();
    #pragma unroll
    for (int kk=0; kk<2; ++kk){
      bf16x8 ah[4];
      #pragma unroll
      for (int i=0;i<4;++i){
        int r = fm + i*16 + lm;
        int kb = ((kk<<6) + (lk<<4)) ^ ((r & 7) << 4);
        ah[i] = *(const bf16x8*)(ldsAh + r*128 + kb);
      }
      #pragma unroll
      for (int j=0;j<4;++j){
        int r = fn + j*16 + lm;
        int kb = ((kk<<6) + (lk<<4)) ^ ((r & 7) << 4);
        bf16x8 bh = *(const bf16x8*)(ldsBh + r*128 + kb);
        #pragma unroll
        for (int i=0;i<4;++i)
          acc[i][j] = __builtin_amdgcn_mfma_f32_16x16x32_bf16(ah[i], bh, acc[i][j], 0, 0, 0);
      }
    }
    __syncthreads();
  }

  float* ldsF = (float*)lds;
  #pragma unroll
  for (int chv=0; chv<4; ++chv){
    __syncthreads();
    if (wm == (chv >> 1)){
      #pragma unroll
      for (int i2=0;i2<2;++i2){
        int i = (chv & 1)*2 + i2;
        #pragma unroll
        for (int j=0;j<4;++j){
          int n = fn + j*16 + lm;
          int m2 = i2*16 + lk*4;
          #pragma unroll
          for (int r2=0;r2<4;++r2) ldsF[(m2+r2)*136 + n] = acc[i][j][r2];
        }
      }
    }
    __syncthreads();
    #pragma unroll
    for (int g2=0; g2<2; ++g2){
      int t2 = g2*256 + tid;
      int rr = t2 >> 4;
      int co = (t2 & 15) * 8;
      float v[8];
      #pragma unroll
      for (int e=0;e<8;++e) v[e] = ldsF[rr*136 + co + e];
      int mg = m0 + chv*32 + rr;
      int ng = n0 + co;
      long oidx = (long)bl*Obl + (long)mg*Ors + ng;
      float b = bias ? bias[mg] : 0.f;
      union { int4 vv; unsigned short u[8]; } hh;
      #pragma unroll
      for (int e=0;e<8;++e) hh.u[e] = f2bf(v[e] + b);
      *(int4*)(O16a + oidx) = hh.vv;
    }
  }
}

// ---------------- final fused kernel (validated round 1) ----------------

__global__ __launch_bounds__(256,2) void k_final(
  const unsigned short* __restrict__ v2T,
  const unsigned short* __restrict__ attn2g,
  const unsigned short* __restrict__ Xhi, const unsigned short* __restrict__ Xlo,
  const unsigned short* __restrict__ W1hi, const unsigned short* __restrict__ W1lo,
  const float* __restrict__ b1eff,
  float* __restrict__ out)
{
  __shared__ char lds[32768];
  char* ldsA = lds; char* ldsB = lds + 16384;
  const int tid = threadIdx.x;
  const int l = tid & 63, wid = tid >> 6;
  const int wm = wid >> 1, wn = wid & 1;
  const int lm = l & 15, lk = l >> 4;
  const int fm = wm*64, fn = wn*64;
  const int bl = blockIdx.z;
  const int m0 = blockIdx.x*128;   // s
  const int n0 = blockIdx.y*128;   // c

  f32x4 acc[4][4];
  #pragma unroll
  for (int i=0;i<4;++i)
    #pragma unroll
    for (int j=0;j<4;++j) acc[i][j] = (f32x4){0.f,0.f,0.f,0.f};

  for (int kt=0; kt<16; ++kt){
    const int ph = kt >> 2;
    const int kq = (kt & 3) << 6;
    if (ph == 0){
      #pragma unroll
      for (int it=0; it<4; ++it){
        int cid = it*256 + tid;
        int d = cid & 63, sc = cid >> 6;
        int dg = kq + d;
        long row = (long)(((bl >> 3)*8 + (dg & 7))*256 + ((bl & 7) << 5) + (dg >> 3));
        union { int4 v; unsigned short u[8]; } ldv;
        ldv.v = *(const int4*)(v2T + row*4096 + m0 + sc*8);
        #pragma unroll
        for (int e=0;e<8;++e){
          int sl = sc*8 + e;
          int bo = sl*128 + ((d*2) ^ ((sl & 7) << 4));
          *(unsigned short*)(ldsA + bo) = ldv.u[e];
        }
      }
      #pragma unroll
      for (int it=0; it<4; ++it){
        int idx = it*256 + tid;
        int r = idx >> 3;
        int kb = ((idx & 7) << 4) ^ ((r & 7) << 4);
        long gbb = (long)bl*65536 + (long)(n0 + r)*256 + kq + (kb >> 1);
        gload16(attn2g + gbb, ldsB + idx*16);
      }
    } else {
      const unsigned short* As = (ph==3) ? Xlo : Xhi;
      const unsigned short* Bs = (ph==2) ? W1lo : W1hi;
      #pragma unroll
      for (int it=0; it<4; ++it){
        int idx = it*256 + tid;
        int r = idx >> 3;
        int kb = ((idx & 7) << 4) ^ ((r & 7) << 4);
        long ga = (long)bl*1048576 + (long)(m0 + r)*256 + kq + (kb >> 1);
        gload16(As + ga, ldsA + idx*16);
        long gbb = (long)bl*65536 + (long)(n0 + r)*256 + kq + (kb >> 1);
        gload16(Bs + gbb, ldsB + idx*16);
      }
    }
    __syncthreads();
    #pragma unroll
    for (int kk=0; kk<2; ++kk){
      bf16x8 a_[4];
      #pragma unroll
      for (int i=0;i<4;++i){
        int r = fm + i*16 + lm;
        int kb = ((kk<<6) + (lk<<4)) ^ ((r & 7) << 4);
        a_[i] = *(const bf16x8*)(ldsA + r*128 + kb);
      }
      #pragma unroll
      for (int j=0;j<4;++j){
        int r = fn + j*16 + lm;
        int kb = ((kk<<6) + (lk<<4)) ^ ((r & 7) << 4);
        bf16x8 b_ = *(const bf16x8*)(ldsB + r*128 + kb);
        #pragma unroll
        for (int i=0;i<4;++i)
          acc[i][j] = __builtin_amdgcn_mfma_f32_16x16x32_bf16(a_[i], b_, acc[i][j], 0, 0, 0);
      }
    }
    __syncthreads();
  }

  float* ldsF = (float*)lds;
  #pragma unroll
  for (int chv=0; chv<4; ++chv){
    __syncthreads();
    if (wm == (chv >> 1)){
      #pragma unroll
      for (int i2=0;i2<2;++i2){
        int i = (chv & 1)*2 + i2;
        #pragma unroll
        for (int j=0;j<4;++j){
          int n = fn + j*16 + lm;
          int m2 = i2*16 + lk*4;
          #pragma unroll
          for (int r2=0;r2<4;++r2) ldsF[(m2+r2)*136 + n] = acc[i][j][r2];
        }
      }
    }
    __syncthreads();
    #pragma unroll
    for (int g2=0; g2<2; ++g2){
      int t2 = g2*256 + tid;
      int rr = t2 >> 4;
      int co = (t2 & 15) * 8;
      int mg = m0 + chv*32 + rr;     // s
      int ng = n0 + co;              // c
      long oidx = (long)bl*1048576 + (long)mg*256 + ng;
      float4 o0, o1;
      o0.x = ldsF[rr*136+co+0] + b1eff[bl*256+ng+0];
      o0.y = ldsF[rr*136+co+1] + b1eff[bl*256+ng+1];
      o0.z = ldsF[rr*136+co+2] + b1eff[bl*256+ng+2];
      o0.w = ldsF[rr*136+co+3] + b1eff[bl*256+ng+3];
      o1.x = ldsF[rr*136+co+4] + b1eff[bl*256+ng+4];
      o1.y = ldsF[rr*136+co+5] + b1eff[bl*256+ng+5];
      o1.z = ldsF[rr*136+co+6] + b1eff[bl*256+ng+6];
      o1.w = ldsF[rr*136+co+7] + b1eff[bl*256+ng+7];
      *(float4*)(out + oidx)     = o0;
      *(float4*)(out + oidx + 4) = o1;
    }
  }
}

// ---------------- launch ----------------

extern "C" void kernel_launch(void* const* d_in, const int* in_sizes, int n_in,
                              void* d_out, int out_size, void* d_ws, size_t ws_size,
                              hipStream_t stream)
{
  const float* x    = (const float*)d_in[0];
  const float* sq_w = (const float*)d_in[3];
  const float* sq_b = (const float*)d_in[4];
  const float* sk_w = (const float*)d_in[5];
  const float* sk_b = (const float*)d_in[6];
  const float* sv_w = (const float*)d_in[7];
  const float* sv_b = (const float*)d_in[8];
  const float* tq_w = (const float*)d_in[9];
  const float* tq_b = (const float*)d_in[10];
  const float* tk_w = (const float*)d_in[11];
  const float* tk_b = (const float*)d_in[12];
  const float* tv_w = (const float*)d_in[13];
  const float* tv_b = (const float*)d_in[14];
  const float* s_g  = (const float*)d_in[15];
  const float* t_g  = (const float*)d_in[16];

  char* p = (char*)d_ws;
  size_t off = 0;
  auto take = [&](size_t n){ char* r = p + off; off = (off + n + 255) & ~(size_t)255; return r; };

  unsigned short* Whi    = (unsigned short*)take((size_t)6*65536*2);
  unsigned short* Wlo    = (unsigned short*)take((size_t)6*65536*2);
  unsigned short* WvThi  = (unsigned short*)take((size_t)65536*2);
  unsigned short* WvTlo  = (unsigned short*)take((size_t)65536*2);
  unsigned short* Xhi    = (unsigned short*)take((size_t)16*S4*CH*2);
  unsigned short* Xlo    = (unsigned short*)take((size_t)16*S4*CH*2);
  unsigned short* v2T    = (unsigned short*)take((size_t)16*S4*CH*2);
  float*          Gp     = (float*)take((size_t)128*65536*4);
  unsigned short* G1hi   = (unsigned short*)take((size_t)16*65536*2);
  unsigned short* G1lo   = (unsigned short*)take((size_t)16*65536*2);
  unsigned short* GShi   = (unsigned short*)take((size_t)16*65536*2);
  unsigned short* GSlo   = (unsigned short*)take((size_t)16*65536*2);
  unsigned short* Pthi   = (unsigned short*)take((size_t)16*65536*2);
  unsigned short* Ptlo   = (unsigned short*)take((size_t)16*65536*2);
  unsigned short* G2hi   = (unsigned short*)take((size_t)16*65536*2);
  unsigned short* G2lo   = (unsigned short*)take((size_t)16*65536*2);
  unsigned short* W1hi   = (unsigned short*)take((size_t)16*65536*2);
  unsigned short* W1lo   = (unsigned short*)take((size_t)16*65536*2);
  unsigned short* a1hi   = (unsigned short*)take((size_t)16*65536*2);
  unsigned short* a1lo   = (unsigned short*)take((size_t)16*65536*2);
  unsigned short* a2g    = (unsigned short*)take((size_t)16*65536*2);
  float*          logits = (float*)take((size_t)16*65536*4);
  float*          ups    = (float*)take((size_t)1024*256*4);
  float*          u      = (float*)take((size_t)16*256*4);
  float*          b1eff  = (float*)take((size_t)16*256*4);

  const long XBL = (long)S4*CH;     // 1048576

  k_wprep<<<dim3(1792), 256, 0, stream>>>(sq_w, sk_w, sv_w, tq_w, tk_w, tv_w,
                                          Whi, Wlo, WvThi, WvTlo);
  k_xprep2<<<dim3(1024), 256, 0, stream>>>(x, Xhi, Xlo, ups);
  k_vecfin<<<dim3(16), 256, 0, stream>>>(ups, u);

  k_gram<false><<<dim3(2,2,128), 256, 0, stream>>>(Xhi, Xlo, Gp);
  k_gcomb<<<dim3(256,16), 256, 0, stream>>>(Gp, G1hi, G1lo);
  k_gram<true><<<dim3(2,2,128), 256, 0, stream>>>(Xhi, Xlo, Gp);
  k_gcomb<<<dim3(256,16), 256, 0, stream>>>(Gp, GShi, GSlo);

  k_mega<<<dim3(16), 512, 0, stream>>>(
     Whi, Wlo, WvThi, WvTlo, G1hi, G1lo, GShi, GSlo,
     sq_w, sk_w, tk_w, tq_w, sq_b, sk_b, sv_b, tq_b, tk_b,
     s_g, t_g, u,
     Pthi, Ptlo, logits, a1hi, a1lo, W1hi, W1lo, G2hi, G2lo, a2g, b1eff);

  // v2 conv: v2T[bl][dv][s] = sum_e Wtv[dv][e] X[s][e] + btv[dv]
  k_gemm<false,1><<<dim3(2,32,16), 256, 0, stream>>>(
     Whi+5*65536, nullptr, 0, 256,  Xhi, nullptr, XBL, 256,
     tv_b, v2T, XBL, S4);

  k_final<<<dim3(32,2,16), 256, 0, stream>>>(v2T, a2g, Xhi, Xlo, W1hi, W1lo, b1eff, (float*)d_out);
}

// Round 4
// 499.027 us; speedup vs baseline: 1.2181x; 1.2181x over previous
//
#include <hip/hip_runtime.h>
#include <stdint.h>

// LossRecovery via Gram-matrix collapse (algebra validated rounds 1-3, absmax 0.031):
//   G1 = X^T X, GS = sum_s x_s x_swap(s)^T (symmetric).
//   logits1 = Wq G1 Wk^T + rank1;  W1 = I + gs*attn1*Wv;  x1 = X W1^T + b1eff (never materialized)
//   logits2 = Wtq (W1 GS + b1eff u^T) Wtk^T + rank1
//   out = gather(v2)·(gt*attn2) + X W1^T + b1eff
// Round 4: mega removed; chain = wide per-stage launches with fused-softmax logit kernels.

#define S4 4096
#define CH 256

typedef __attribute__((ext_vector_type(8))) short bf16x8;
typedef __attribute__((ext_vector_type(4))) float f32x4;

static __device__ __forceinline__ float bf2f(unsigned short u){
  union { unsigned int i; float f; } v; v.i = ((unsigned int)u) << 16; return v.f;
}
static __device__ __forceinline__ unsigned short f2bf(float f){
  union { float f; unsigned int i; } v; v.f = f;
  unsigned int x = v.i;
  x += 0x7fffu + ((x >> 16) & 1u);   // RNE
  return (unsigned short)(x >> 16);
}
static __device__ __forceinline__ void gload16(const void* g, void* l){
  __builtin_amdgcn_global_load_lds((const __attribute__((address_space(1))) void*)g,
                                   (__attribute__((address_space(3))) void*)l, 16, 0, 0);
}

// ---------------- prep ----------------

__global__ void k_xprep2(const float* __restrict__ x,
                         unsigned short* __restrict__ xhi,
                         unsigned short* __restrict__ xlo,
                         float* __restrict__ ups){
  int blk = blockIdx.x;            // 0..1023
  int c   = threadIdx.x;           // 0..255
  long rbase = (long)blk * 64;
  float s = 0.f;
  for (int i = 0; i < 64; ++i){
    long row = rbase + i;
    float v = x[row*259 + c];
    unsigned short h = f2bf(v);
    xhi[row*256 + c] = h;
    xlo[row*256 + c] = f2bf(v - bf2f(h));
    s += v;
  }
  ups[(long)blk*256 + c] = s;
}

__global__ void k_vecfin(const float* __restrict__ ups, float* __restrict__ u){
  int bl = blockIdx.x, e = threadIdx.x;
  float s = 0.f;
  for (int ch = 0; ch < 64; ++ch) s += ups[(long)(bl*64 + ch)*256 + e];
  u[bl*256 + e] = s;
}

__global__ void k_wprep(const float* __restrict__ w0, const float* __restrict__ w1,
                        const float* __restrict__ w2, const float* __restrict__ w3,
                        const float* __restrict__ w4, const float* __restrict__ w5,
                        unsigned short* __restrict__ whi, unsigned short* __restrict__ wlo,
                        unsigned short* __restrict__ wvthi, unsigned short* __restrict__ wvtlo){
  int i = blockIdx.x*256 + threadIdx.x;   // 0 .. 7*65536
  int mat = i >> 16; int off = i & 65535;
  if (mat < 6){
    const float* src = mat==0?w0:mat==1?w1:mat==2?w2:mat==3?w3:mat==4?w4:w5;
    float v = src[off];
    unsigned short h = f2bf(v);
    whi[i] = h;
    wlo[i] = f2bf(v - bf2f(h));
  } else {
    int e = off >> 8, d = off & 255;
    float v = w2[d*256 + e];              // WvT[e][d] = sv_w[d][e]
    unsigned short h = f2bf(v);
    wvthi[off] = h;
    wvtlo[off] = f2bf(v - bf2f(h));
  }
}

// wqu'[c] = Wq u + 4096*bq ; wku = Wk u ; wtku = Wtk u   (validated round 2)
__global__ void k_vec1(const float* __restrict__ sq_w, const float* __restrict__ sq_b,
                       const float* __restrict__ sk_w, const float* __restrict__ tk_w,
                       const float* __restrict__ u,
                       float* __restrict__ wqu, float* __restrict__ wku, float* __restrict__ wtku){
  int bl = blockIdx.x, mat = blockIdx.y;
  const float* W = mat==0? sq_w : mat==1? sk_w : tk_w;
  int l = threadIdx.x & 63, w = threadIdx.x >> 6;
  const float* ub = u + bl*256;
  for (int i=0;i<64;++i){
    int c = w*64 + i;
    float s = 0.f;
    #pragma unroll
    for (int j=0;j<4;++j) s += W[c*256 + l + 64*j] * ub[l + 64*j];
    #pragma unroll
    for (int off=32; off; off>>=1) s += __shfl_xor(s, off, 64);
    if (l==0){
      if (mat==0) wqu [bl*256+c] = s + 4096.f*sq_b[c];
      else if (mat==1) wku [bl*256+c] = s;
      else wtku[bl*256+c] = s;
    }
  }
}

// b1eff = gs*c1 ; h1 = ph1 + 4096*b1eff ; wtqh'[c] = Wtq h1 + 4096*btq
__global__ void k_vec2(const float* __restrict__ ph1_g, const float* __restrict__ c1_g,
                       const float* __restrict__ s_gp,
                       const float* __restrict__ tq_w, const float* __restrict__ tq_b,
                       float* __restrict__ b1eff_g, float* __restrict__ wtqh){
  __shared__ float h1[256];
  int bl = blockIdx.x, tid = threadIdx.x;
  float gs = s_gp[0];
  float b1 = gs * c1_g[bl*256 + tid];
  b1eff_g[bl*256 + tid] = b1;
  h1[tid] = ph1_g[bl*256 + tid] + 4096.f*b1;
  __syncthreads();
  float s = 0.f;
  #pragma unroll 4
  for (int e = 0; e < 256; e += 4){
    float4 w = *(const float4*)(tq_w + tid*256 + e);
    s += w.x*h1[e] + w.y*h1[e+1] + w.z*h1[e+2] + w.w*h1[e+3];
  }
  wtqh[bl*256 + tid] = s + 4096.f*tq_b[tid];
}

// combine 8 Gram partials -> hi/lo
__global__ void k_gcomb(const float* __restrict__ Gp,
                        unsigned short* __restrict__ ghi, unsigned short* __restrict__ glo){
  int bl = blockIdx.y;
  int idx = blockIdx.x*256 + threadIdx.x;
  float s = 0.f;
  #pragma unroll
  for (int p = 0; p < 8; ++p) s += Gp[(long)(bl*8 + p)*65536 + idx];
  unsigned short h = f2bf(s);
  ghi[(long)bl*65536 + idx] = h;
  glo[(long)bl*65536 + idx] = f2bf(s - bf2f(h));
}

// ---------------- Gram kernel (validated round 3) ----------------

template<bool BSWAP>
__global__ __launch_bounds__(256) void k_gram(
  const unsigned short* __restrict__ Xhi, const unsigned short* __restrict__ Xlo,
  float* __restrict__ Gp)
{
  __shared__ char lds[65536];
  char* ldsAh = lds;
  char* ldsAl = lds + 16384;
  char* ldsBh = lds + 32768;
  char* ldsBl = lds + 49152;

  const int tid = threadIdx.x;
  const int l = tid & 63, wid = tid >> 6;
  const int wm = wid >> 1, wn = wid & 1;
  const int lm = l & 15, lk = l >> 4;
  const int fm = wm*64, fn = wn*64;

  int flat = blockIdx.x + 2*(blockIdx.y + 2*blockIdx.z);
  int lg = (flat & 7)*64 + (flat >> 3);
  const int m0 = (lg & 1)*128;
  const int n0 = ((lg >> 1) & 1)*128;
  const int zz = lg >> 2;
  const int bl = zz >> 3, sp = zz & 7;
  const long Xoff = (long)bl * (4096*256);

  const int sg = tid & 15;
  const int eg = tid >> 4;

  f32x4 acc[4][4];
  #pragma unroll
  for (int i=0;i<4;++i)
    #pragma unroll
    for (int j=0;j<4;++j) acc[i][j] = (f32x4){0.f,0.f,0.f,0.f};

  union U4 { int4 v; unsigned short u[8]; };

  for (int kt = 0; kt < 8; ++kt){
    const int k0 = sp*512 + kt*64;
    U4 va[4], vla[4], vb[4], vlb[4];
    #pragma unroll
    for (int ss = 0; ss < 4; ++ss){
      int sa = k0 + sg*4 + ss;
      int sb = BSWAP ? (((sa & 63) << 6) | (sa >> 6)) : sa;
      long gaA = Xoff + (long)sa*256 + m0 + eg*8;
      long gaB = Xoff + (long)sb*256 + n0 + eg*8;
      va[ss].v  = *(const int4*)(Xhi + gaA);
      vla[ss].v = *(const int4*)(Xlo + gaA);
      vb[ss].v  = *(const int4*)(Xhi + gaB);
      vlb[ss].v = *(const int4*)(Xlo + gaB);
    }
    #pragma unroll
    for (int j = 0; j < 8; ++j){
      int e_loc = eg*8 + j;
      int bo = e_loc*128 + ((sg*8) ^ (j << 4));
      ushort4 t;
      t.x=va[0].u[j];  t.y=va[1].u[j];  t.z=va[2].u[j];  t.w=va[3].u[j];
      *(ushort4*)(ldsAh + bo) = t;
      t.x=vla[0].u[j]; t.y=vla[1].u[j]; t.z=vla[2].u[j]; t.w=vla[3].u[j];
      *(ushort4*)(ldsAl + bo) = t;
      t.x=vb[0].u[j];  t.y=vb[1].u[j];  t.z=vb[2].u[j];  t.w=vb[3].u[j];
      *(ushort4*)(ldsBh + bo) = t;
      t.x=vlb[0].u[j]; t.y=vlb[1].u[j]; t.z=vlb[2].u[j]; t.w=vlb[3].u[j];
      *(ushort4*)(ldsBl + bo) = t;
    }
    __syncthreads();
    #pragma unroll
    for (int kk = 0; kk < 2; ++kk){
      bf16x8 ah[4], al_[4];
      #pragma unroll
      for (int i=0;i<4;++i){
        int r = fm + i*16 + lm;
        int kb = ((kk<<6) + (lk<<4)) ^ ((r & 7) << 4);
        ah[i]  = *(const bf16x8*)(ldsAh + r*128 + kb);
        al_[i] = *(const bf16x8*)(ldsAl + r*128 + kb);
      }
      #pragma unroll
      for (int j=0;j<4;++j){
        int r = fn + j*16 + lm;
        int kb = ((kk<<6) + (lk<<4)) ^ ((r & 7) << 4);
        bf16x8 bh  = *(const bf16x8*)(ldsBh + r*128 + kb);
        bf16x8 bl8 = *(const bf16x8*)(ldsBl + r*128 + kb);
        #pragma unroll
        for (int i=0;i<4;++i){
          acc[i][j] = __builtin_amdgcn_mfma_f32_16x16x32_bf16(ah[i], bh, acc[i][j], 0, 0, 0);
          acc[i][j] = __builtin_amdgcn_mfma_f32_16x16x32_bf16(ah[i], bl8, acc[i][j], 0, 0, 0);
          acc[i][j] = __builtin_amdgcn_mfma_f32_16x16x32_bf16(al_[i], bh, acc[i][j], 0, 0, 0);
        }
      }
    }
    __syncthreads();
  }

  float* ldsF = (float*)lds;
  #pragma unroll
  for (int chv = 0; chv < 4; ++chv){
    __syncthreads();
    if (wm == (chv >> 1)){
      #pragma unroll
      for (int i2=0;i2<2;++i2){
        int i = (chv & 1)*2 + i2;
        #pragma unroll
        for (int j=0;j<4;++j){
          int n = fn + j*16 + lm;
          int m2 = i2*16 + lk*4;
          #pragma unroll
          for (int r2=0;r2<4;++r2) ldsF[(m2+r2)*136 + n] = acc[i][j][r2];
        }
      }
    }
    __syncthreads();
    #pragma unroll
    for (int g2 = 0; g2 < 2; ++g2){
      int t2 = g2*256 + tid;
      int rr = t2 >> 4;
      int co = (t2 & 15) * 8;
      int mg = m0 + chv*32 + rr;
      int ng = n0 + co;
      long oidx = (long)zz*65536 + (long)mg*256 + ng;
      float4 o0, o1;
      o0.x = ldsF[rr*136+co+0]; o0.y = ldsF[rr*136+co+1];
      o0.z = ldsF[rr*136+co+2]; o0.w = ldsF[rr*136+co+3];
      o1.x = ldsF[rr*136+co+4]; o1.y = ldsF[rr*136+co+5];
      o1.z = ldsF[rr*136+co+6]; o1.w = ldsF[rr*136+co+7];
      *(float4*)(Gp + oidx)     = o0;
      *(float4*)(Gp + oidx + 4) = o1;
    }
  }
}

// ---------------- chain GEMM: 128x128 tile, K=256, split 3-pass ----------------
// C[m][n] = sum_k (Ah+Al)[m][k]*(Bh+Bl)[n][k].  A shared (weights or per-frame via Abl),
// B per-frame via Bbl. OUT_MODE: 0 = bf16 hi/lo (+opt rank1 ra1[m]*rb1[n]);
//                       2 = W1 = I + gs*acc (hi/lo) + atomic h1[m] += sum_n W1*u[n].

template<int OUT_MODE>
__global__ __launch_bounds__(256) void k_cgemm(
  const unsigned short* __restrict__ Ah, const unsigned short* __restrict__ Al, long Abl,
  const unsigned short* __restrict__ Bh, const unsigned short* __restrict__ Bl, long Bbl,
  const float* __restrict__ ra1, int ra1st, const float* __restrict__ rb1, int rb1st,
  const float* __restrict__ gsp, const float* __restrict__ u_g, float* __restrict__ ph1_g,
  unsigned short* __restrict__ Oh, unsigned short* __restrict__ Ol)
{
  __shared__ char lds[65536];
  char* ldsAh = lds;
  char* ldsAl = lds + 16384;
  char* ldsBh = lds + 32768;
  char* ldsBl = lds + 49152;

  const int tid = threadIdx.x;
  const int l   = tid & 63;
  const int wid = tid >> 6;
  const int wm  = wid >> 1, wn = wid & 1;
  const int lm  = l & 15, lk = l >> 4;
  const int fm  = wm*64, fn = wn*64;
  const int bl  = blockIdx.z;
  const int m0  = blockIdx.x * 128;
  const int n0  = blockIdx.y * 128;

  f32x4 acc[4][4];
  #pragma unroll
  for (int i=0;i<4;++i)
    #pragma unroll
    for (int j=0;j<4;++j) acc[i][j] = (f32x4){0.f,0.f,0.f,0.f};

  for (int kt = 0; kt < 4; ++kt){
    const int kq = kt << 6;
    #pragma unroll
    for (int it=0; it<4; ++it){
      int idx = it*256 + tid;
      int r = idx >> 3;
      int kb = ((idx & 7) << 4) ^ ((r & 7) << 4);
      long ga = (long)bl*Abl + (long)(m0 + r)*256 + kq + (kb >> 1);
      gload16(Ah + ga, ldsAh + idx*16);
      gload16(Al + ga, ldsAl + idx*16);
      long gbb = (long)bl*Bbl + (long)(n0 + r)*256 + kq + (kb >> 1);
      gload16(Bh + gbb, ldsBh + idx*16);
      gload16(Bl + gbb, ldsBl + idx*16);
    }
    __syncthreads();
    #pragma unroll
    for (int kk=0; kk<2; ++kk){
      bf16x8 ah[4], al_[4];
      #pragma unroll
      for (int i=0;i<4;++i){
        int r = fm + i*16 + lm;
        int kb = ((kk<<6) + (lk<<4)) ^ ((r & 7) << 4);
        ah[i]  = *(const bf16x8*)(ldsAh + r*128 + kb);
        al_[i] = *(const bf16x8*)(ldsAl + r*128 + kb);
      }
      #pragma unroll
      for (int j=0;j<4;++j){
        int r = fn + j*16 + lm;
        int kb = ((kk<<6) + (lk<<4)) ^ ((r & 7) << 4);
        bf16x8 bh  = *(const bf16x8*)(ldsBh + r*128 + kb);
        bf16x8 bl8 = *(const bf16x8*)(ldsBl + r*128 + kb);
        #pragma unroll
        for (int i=0;i<4;++i){
          acc[i][j] = __builtin_amdgcn_mfma_f32_16x16x32_bf16(ah[i], bh, acc[i][j], 0, 0, 0);
          acc[i][j] = __builtin_amdgcn_mfma_f32_16x16x32_bf16(ah[i], bl8, acc[i][j], 0, 0, 0);
          acc[i][j] = __builtin_amdgcn_mfma_f32_16x16x32_bf16(al_[i], bh, acc[i][j], 0, 0, 0);
        }
      }
    }
    __syncthreads();
  }

  float gs = (OUT_MODE==2) ? gsp[0] : 0.f;
  float* ldsF = (float*)lds;
  #pragma unroll
  for (int chv=0; chv<4; ++chv){
    __syncthreads();
    if (wm == (chv >> 1)){
      #pragma unroll
      for (int i2=0;i2<2;++i2){
        int i = (chv & 1)*2 + i2;
        #pragma unroll
        for (int j=0;j<4;++j){
          int n = fn + j*16 + lm;
          int m2 = i2*16 + lk*4;
          #pragma unroll
          for (int r2=0;r2<4;++r2) ldsF[(m2+r2)*136 + n] = acc[i][j][r2];
        }
      }
    }
    __syncthreads();
    #pragma unroll
    for (int g2=0; g2<2; ++g2){
      int t2 = g2*256 + tid;
      int rr = t2 >> 4;
      int co = (t2 & 15) * 8;
      float v[8];
      #pragma unroll
      for (int e=0;e<8;++e) v[e] = ldsF[rr*136 + co + e];
      int mg = m0 + chv*32 + rr;
      int ng = n0 + co;
      long oidx = (long)bl*65536 + (long)mg*256 + ng;
      if (OUT_MODE == 0){
        if (ra1){
          float a1v = ra1[bl*ra1st + mg];
          #pragma unroll
          for (int e=0;e<8;++e) v[e] += a1v * rb1[bl*rb1st + ng + e];
        }
      }
      if (OUT_MODE == 2){
        float hs = 0.f;
        #pragma unroll
        for (int e=0;e<8;++e){
          float w = ((mg == ng + e) ? 1.f : 0.f) + gs*v[e];
          hs += w * u_g[bl*256 + ng + e];
          v[e] = w;
        }
        atomicAdd(ph1_g + bl*256 + mg, hs);
      }
      union { int4 vv; unsigned short us[8]; } hh, ll;
      #pragma unroll
      for (int e=0;e<8;++e) hh.us[e] = f2bf(v[e]);
      *(int4*)(Oh + oidx) = hh.vv;
      #pragma unroll
      for (int e=0;e<8;++e) ll.us[e] = f2bf(v[e] - bf2f(hh.us[e]));
      *(int4*)(Ol + oidx) = ll.vv;
    }
  }
}

// ---------------- logits + fused softmax ----------------
// tile: 128 m-rows x 256 n-cols (full softmax row in-block), 8 waves.
// L[m][n] = sum_k (Ah+Al)[m][k]*(Bh+Bl)[n][k] + ra1[m]*rb1[n] + ra2[m]*rb2[n]
// SMODE 0: p = softmax -> Oh/Ol hi/lo + c1[m] = sum_n p*bv[n].  SMODE 1: Oh = tg*softmax (hi only).

template<int SMODE>
__global__ __launch_bounds__(512) void k_logit(
  const unsigned short* __restrict__ Ah, const unsigned short* __restrict__ Al,
  const unsigned short* __restrict__ Bh, const unsigned short* __restrict__ Bl,
  const float* __restrict__ ra1, int ra1st, const float* __restrict__ rb1, int rb1st,
  const float* __restrict__ ra2, int ra2st, const float* __restrict__ rb2, int rb2st,
  const float* __restrict__ bvp, const float* __restrict__ tgp,
  float* __restrict__ c1_g,
  unsigned short* __restrict__ Oh, unsigned short* __restrict__ Ol)
{
  __shared__ char lds[98304];
  char* ldsAh = lds;
  char* ldsAl = lds + 16384;
  char* ldsBh = lds + 32768;
  char* ldsBl = lds + 65536;

  const int tid = threadIdx.x;
  const int l   = tid & 63;
  const int wid = tid >> 6;
  const int wm  = wid >> 2, wn = wid & 3;
  const int lm  = l & 15, lk = l >> 4;
  const int fm  = wm*64, fn = wn*64;
  const int bl  = blockIdx.z;
  const int m0  = blockIdx.x * 128;

  f32x4 acc[4][4];
  #pragma unroll
  for (int i=0;i<4;++i)
    #pragma unroll
    for (int j=0;j<4;++j) acc[i][j] = (f32x4){0.f,0.f,0.f,0.f};

  for (int kt = 0; kt < 4; ++kt){
    const int kq = kt << 6;
    #pragma unroll
    for (int it=0; it<2; ++it){        // A: 128 rows x 64 k
      int idx = it*512 + tid;
      int r = idx >> 3;
      int kb = ((idx & 7) << 4) ^ ((r & 7) << 4);
      long ga = (long)(m0 + r)*256 + kq + (kb >> 1);
      gload16(Ah + ga, ldsAh + idx*16);
      gload16(Al + ga, ldsAl + idx*16);
    }
    #pragma unroll
    for (int it=0; it<4; ++it){        // B: 256 rows x 64 k
      int idx = it*512 + tid;
      int r = idx >> 3;
      int kb = ((idx & 7) << 4) ^ ((r & 7) << 4);
      long gbb = (long)bl*65536 + (long)r*256 + kq + (kb >> 1);
      gload16(Bh + gbb, ldsBh + idx*16);
      gload16(Bl + gbb, ldsBl + idx*16);
    }
    __syncthreads();
    #pragma unroll
    for (int kk=0; kk<2; ++kk){
      bf16x8 ah[4], al_[4];
      #pragma unroll
      for (int i=0;i<4;++i){
        int r = fm + i*16 + lm;
        int kb = ((kk<<6) + (lk<<4)) ^ ((r & 7) << 4);
        ah[i]  = *(const bf16x8*)(ldsAh + r*128 + kb);
        al_[i] = *(const bf16x8*)(ldsAl + r*128 + kb);
      }
      #pragma unroll
      for (int j=0;j<4;++j){
        int r = fn + j*16 + lm;
        int kb = ((kk<<6) + (lk<<4)) ^ ((r & 7) << 4);
        bf16x8 bh  = *(const bf16x8*)(ldsBh + r*128 + kb);
        bf16x8 bl8 = *(const bf16x8*)(ldsBl + r*128 + kb);
        #pragma unroll
        for (int i=0;i<4;++i){
          acc[i][j] = __builtin_amdgcn_mfma_f32_16x16x32_bf16(ah[i], bh, acc[i][j], 0, 0, 0);
          acc[i][j] = __builtin_amdgcn_mfma_f32_16x16x32_bf16(ah[i], bl8, acc[i][j], 0, 0, 0);
          acc[i][j] = __builtin_amdgcn_mfma_f32_16x16x32_bf16(al_[i], bh, acc[i][j], 0, 0, 0);
        }
      }
    }
    __syncthreads();
  }

  const float tg = (SMODE==1) ? tgp[0] : 1.f;
  float* ldsF = (float*)lds;             // [32][264]
  #pragma unroll
  for (int chv=0; chv<4; ++chv){
    __syncthreads();
    if (wm == (chv >> 1)){
      #pragma unroll
      for (int i2=0;i2<2;++i2){
        int i = (chv & 1)*2 + i2;
        #pragma unroll
        for (int j=0;j<4;++j){
          int n = fn + j*16 + lm;
          int m2 = i2*16 + lk*4;
          #pragma unroll
          for (int r2=0;r2<4;++r2) ldsF[(m2+r2)*264 + n] = acc[i][j][r2];
        }
      }
    }
    __syncthreads();
    // 512 threads: row = tid>>4 (0..31), colgroup = tid&15 -> 16 cols
    {
      int rr  = tid >> 4;
      int ng0 = (tid & 15) * 16;
      int mg  = m0 + chv*32 + rr;
      float v[16];
      #pragma unroll
      for (int e=0;e<16;++e) v[e] = ldsF[rr*264 + ng0 + e];
      float a1v = ra1[bl*ra1st + mg];
      float a2v = ra2[bl*ra2st + mg];
      #pragma unroll
      for (int e=0;e<16;++e)
        v[e] += a1v*rb1[bl*rb1st + ng0 + e] + a2v*rb2[bl*rb2st + ng0 + e];
      float mx = v[0];
      #pragma unroll
      for (int e=1;e<16;++e) mx = fmaxf(mx, v[e]);
      #pragma unroll
      for (int off=1; off<16; off<<=1) mx = fmaxf(mx, __shfl_xor(mx, off, 64));
      float sum = 0.f, dot = 0.f;
      #pragma unroll
      for (int e=0;e<16;++e){
        v[e] = __expf(v[e] - mx);
        sum += v[e];
        if (SMODE == 0) dot += v[e] * bvp[ng0 + e];
      }
      #pragma unroll
      for (int off=1; off<16; off<<=1){
        sum += __shfl_xor(sum, off, 64);
        if (SMODE == 0) dot += __shfl_xor(dot, off, 64);
      }
      float inv = tg / sum;
      long oidx = (long)bl*65536 + (long)mg*256 + ng0;
      union { int4 vv; unsigned short us[8]; } hh, ll;
      #pragma unroll
      for (int half=0; half<2; ++half){
        #pragma unroll
        for (int e=0;e<8;++e) hh.us[e] = f2bf(v[half*8+e] * inv);
        *(int4*)(Oh + oidx + half*8) = hh.vv;
        if (SMODE == 0){
          #pragma unroll
          for (int e=0;e<8;++e) ll.us[e] = f2bf(v[half*8+e]*inv - bf2f(hh.us[e]));
          *(int4*)(Ol + oidx + half*8) = ll.vv;
        }
      }
      if (SMODE == 0 && (tid & 15) == 0) c1_g[bl*256 + mg] = dot / sum;
    }
  }
}

// ---------------- v2 conv (plain bf16, validated) ----------------

__global__ __launch_bounds__(256) void k_vconv(
  const unsigned short* __restrict__ Ah,         // Wtv hi
  const unsigned short* __restrict__ Bh,         // Xhi per-frame
  const float* __restrict__ bias,
  unsigned short* __restrict__ O16a)             // v2T [bl][d][s]
{
  __shared__ char lds[32768];
  char* ldsAh = lds;
  char* ldsBh = lds + 16384;

  const int tid = threadIdx.x;
  const int l   = tid & 63;
  const int wid = tid >> 6;
  const int wm  = wid >> 1, wn = wid & 1;
  const int lm  = l & 15, lk = l >> 4;
  const int fm  = wm*64, fn = wn*64;
  const int bl  = blockIdx.z;
  const int m0  = blockIdx.x * 128;
  const int n0  = blockIdx.y * 128;

  f32x4 acc[4][4];
  #pragma unroll
  for (int i=0;i<4;++i)
    #pragma unroll
    for (int j=0;j<4;++j) acc[i][j] = (f32x4){0.f,0.f,0.f,0.f};

  for (int kt = 0; kt < 4; ++kt){
    const int kq = kt << 6;
    #pragma unroll
    for (int it=0; it<4; ++it){
      int idx = it*256 + tid;
      int r = idx >> 3;
      int kb = ((idx & 7) << 4) ^ ((r & 7) << 4);
      long ga = (long)(m0 + r)*256 + kq + (kb >> 1);
      gload16(Ah + ga, ldsAh + idx*16);
      long gbb = (long)bl*1048576 + (long)(n0 + r)*256 + kq + (kb >> 1);
      gload16(Bh + gbb, ldsBh + idx*16);
    }
    __syncthreads();
    #pragma unroll
    for (int kk=0; kk<2; ++kk){
      bf16x8 ah[4];
      #pragma unroll
      for (int i=0;i<4;++i){
        int r = fm + i*16 + lm;
        int kb = ((kk<<6) + (lk<<4)) ^ ((r & 7) << 4);
        ah[i] = *(const bf16x8*)(ldsAh + r*128 + kb);
      }
      #pragma unroll
      for (int j=0;j<4;++j){
        int r = fn + j*16 + lm;
        int kb = ((kk<<6) + (lk<<4)) ^ ((r & 7) << 4);
        bf16x8 bh = *(const bf16x8*)(ldsBh + r*128 + kb);
        #pragma unroll
        for (int i=0;i<4;++i)
          acc[i][j] = __builtin_amdgcn_mfma_f32_16x16x32_bf16(ah[i], bh, acc[i][j], 0, 0, 0);
      }
    }
    __syncthreads();
  }

  float* ldsF = (float*)lds;
  #pragma unroll
  for (int chv=0; chv<4; ++chv){
    __syncthreads();
    if (wm == (chv >> 1)){
      #pragma unroll
      for (int i2=0;i2<2;++i2){
        int i = (chv & 1)*2 + i2;
        #pragma unroll
        for (int j=0;j<4;++j){
          int n = fn + j*16 + lm;
          int m2 = i2*16 + lk*4;
          #pragma unroll
          for (int r2=0;r2<4;++r2) ldsF[(m2+r2)*136 + n] = acc[i][j][r2];
        }
      }
    }
    __syncthreads();
    #pragma unroll
    for (int g2=0; g2<2; ++g2){
      int t2 = g2*256 + tid;
      int rr = t2 >> 4;
      int co = (t2 & 15) * 8;
      int mg = m0 + chv*32 + rr;     // d
      int ng = n0 + co;              // s
      long oidx = (long)bl*1048576 + (long)mg*4096 + ng;
      float b = bias[mg];
      union { int4 vv; unsigned short us[8]; } hh;
      #pragma unroll
      for (int e=0;e<8;++e) hh.us[e] = f2bf(ldsF[rr*136 + co + e] + b);
      *(int4*)(O16a + oidx) = hh.vv;
    }
  }
}

// ---------------- final fused kernel (validated round 1) ----------------

__global__ __launch_bounds__(256,2) void k_final(
  const unsigned short* __restrict__ v2T,
  const unsigned short* __restrict__ attn2g,
  const unsigned short* __restrict__ Xhi, const unsigned short* __restrict__ Xlo,
  const unsigned short* __restrict__ W1hi, const unsigned short* __restrict__ W1lo,
  const float* __restrict__ b1eff,
  float* __restrict__ out)
{
  __shared__ char lds[32768];
  char* ldsA = lds; char* ldsB = lds + 16384;
  const int tid = threadIdx.x;
  const int l = tid & 63, wid = tid >> 6;
  const int wm = wid >> 1, wn = wid & 1;
  const int lm = l & 15, lk = l >> 4;
  const int fm = wm*64, fn = wn*64;
  const int bl = blockIdx.z;
  const int m0 = blockIdx.x*128;   // s
  const int n0 = blockIdx.y*128;   // c

  f32x4 acc[4][4];
  #pragma unroll
  for (int i=0;i<4;++i)
    #pragma unroll
    for (int j=0;j<4;++j) acc[i][j] = (f32x4){0.f,0.f,0.f,0.f};

  for (int kt=0; kt<16; ++kt){
    const int ph = kt >> 2;
    const int kq = (kt & 3) << 6;
    if (ph == 0){
      #pragma unroll
      for (int it=0; it<4; ++it){
        int cid = it*256 + tid;
        int d = cid & 63, sc = cid >> 6;
        int dg = kq + d;
        long row = (long)(((bl >> 3)*8 + (dg & 7))*256 + ((bl & 7) << 5) + (dg >> 3));
        union { int4 v; unsigned short u[8]; } ldv;
        ldv.v = *(const int4*)(v2T + row*4096 + m0 + sc*8);
        #pragma unroll
        for (int e=0;e<8;++e){
          int sl = sc*8 + e;
          int bo = sl*128 + ((d*2) ^ ((sl & 7) << 4));
          *(unsigned short*)(ldsA + bo) = ldv.u[e];
        }
      }
      #pragma unroll
      for (int it=0; it<4; ++it){
        int idx = it*256 + tid;
        int r = idx >> 3;
        int kb = ((idx & 7) << 4) ^ ((r & 7) << 4);
        long gbb = (long)bl*65536 + (long)(n0 + r)*256 + kq + (kb >> 1);
        gload16(attn2g + gbb, ldsB + idx*16);
      }
    } else {
      const unsigned short* As = (ph==3) ? Xlo : Xhi;
      const unsigned short* Bs = (ph==2) ? W1lo : W1hi;
      #pragma unroll
      for (int it=0; it<4; ++it){
        int idx = it*256 + tid;
        int r = idx >> 3;
        int kb = ((idx & 7) << 4) ^ ((r & 7) << 4);
        long ga = (long)bl*1048576 + (long)(m0 + r)*256 + kq + (kb >> 1);
        gload16(As + ga, ldsA + idx*16);
        long gbb = (long)bl*65536 + (long)(n0 + r)*256 + kq + (kb >> 1);
        gload16(Bs + gbb, ldsB + idx*16);
      }
    }
    __syncthreads();
    #pragma unroll
    for (int kk=0; kk<2; ++kk){
      bf16x8 a_[4];
      #pragma unroll
      for (int i=0;i<4;++i){
        int r = fm + i*16 + lm;
        int kb = ((kk<<6) + (lk<<4)) ^ ((r & 7) << 4);
        a_[i] = *(const bf16x8*)(ldsA + r*128 + kb);
      }
      #pragma unroll
      for (int j=0;j<4;++j){
        int r = fn + j*16 + lm;
        int kb = ((kk<<6) + (lk<<4)) ^ ((r & 7) << 4);
        bf16x8 b_ = *(const bf16x8*)(ldsB + r*128 + kb);
        #pragma unroll
        for (int i=0;i<4;++i)
          acc[i][j] = __builtin_amdgcn_mfma_f32_16x16x32_bf16(a_[i], b_, acc[i][j], 0, 0, 0);
      }
    }
    __syncthreads();
  }

  float* ldsF = (float*)lds;
  #pragma unroll
  for (int chv=0; chv<4; ++chv){
    __syncthreads();
    if (wm == (chv >> 1)){
      #pragma unroll
      for (int i2=0;i2<2;++i2){
        int i = (chv & 1)*2 + i2;
        #pragma unroll
        for (int j=0;j<4;++j){
          int n = fn + j*16 + lm;
          int m2 = i2*16 + lk*4;
          #pragma unroll
          for (int r2=0;r2<4;++r2) ldsF[(m2+r2)*136 + n] = acc[i][j][r2];
        }
      }
    }
    __syncthreads();
    #pragma unroll
    for (int g2=0; g2<2; ++g2){
      int t2 = g2*256 + tid;
      int rr = t2 >> 4;
      int co = (t2 & 15) * 8;
      int mg = m0 + chv*32 + rr;     // s
      int ng = n0 + co;              // c
      long oidx = (long)bl*1048576 + (long)mg*256 + ng;
      float4 o0, o1;
      o0.x = ldsF[rr*136+co+0] + b1eff[bl*256+ng+0];
      o0.y = ldsF[rr*136+co+1] + b1eff[bl*256+ng+1];
      o0.z = ldsF[rr*136+co+2] + b1eff[bl*256+ng+2];
      o0.w = ldsF[rr*136+co+3] + b1eff[bl*256+ng+3];
      o1.x = ldsF[rr*136+co+4] + b1eff[bl*256+ng+4];
      o1.y = ldsF[rr*136+co+5] + b1eff[bl*256+ng+5];
      o1.z = ldsF[rr*136+co+6] + b1eff[bl*256+ng+6];
      o1.w = ldsF[rr*136+co+7] + b1eff[bl*256+ng+7];
      *(float4*)(out + oidx)     = o0;
      *(float4*)(out + oidx + 4) = o1;
    }
  }
}

// ---------------- launch ----------------

extern "C" void kernel_launch(void* const* d_in, const int* in_sizes, int n_in,
                              void* d_out, int out_size, void* d_ws, size_t ws_size,
                              hipStream_t stream)
{
  const float* x    = (const float*)d_in[0];
  const float* sq_w = (const float*)d_in[3];
  const float* sq_b = (const float*)d_in[4];
  const float* sk_w = (const float*)d_in[5];
  const float* sk_b = (const float*)d_in[6];
  const float* sv_w = (const float*)d_in[7];
  const float* sv_b = (const float*)d_in[8];
  const float* tq_w = (const float*)d_in[9];
  const float* tq_b = (const float*)d_in[10];
  const float* tk_w = (const float*)d_in[11];
  const float* tk_b = (const float*)d_in[12];
  const float* tv_w = (const float*)d_in[13];
  const float* tv_b = (const float*)d_in[14];
  const float* s_g  = (const float*)d_in[15];
  const float* t_g  = (const float*)d_in[16];

  char* p = (char*)d_ws;
  size_t off = 0;
  auto take = [&](size_t n){ char* r = p + off; off = (off + n + 255) & ~(size_t)255; return r; };

  unsigned short* Whi    = (unsigned short*)take((size_t)6*65536*2);
  unsigned short* Wlo    = (unsigned short*)take((size_t)6*65536*2);
  unsigned short* WvThi  = (unsigned short*)take((size_t)65536*2);
  unsigned short* WvTlo  = (unsigned short*)take((size_t)65536*2);
  unsigned short* Xhi    = (unsigned short*)take((size_t)16*S4*CH*2);
  unsigned short* Xlo    = (unsigned short*)take((size_t)16*S4*CH*2);
  unsigned short* v2T    = (unsigned short*)take((size_t)16*S4*CH*2);
  float*          Gp     = (float*)take((size_t)128*65536*4);
  unsigned short* G1hi   = (unsigned short*)take((size_t)16*65536*2);
  unsigned short* G1lo   = (unsigned short*)take((size_t)16*65536*2);
  unsigned short* GShi   = (unsigned short*)take((size_t)16*65536*2);
  unsigned short* GSlo   = (unsigned short*)take((size_t)16*65536*2);
  unsigned short* Pthi   = (unsigned short*)take((size_t)16*65536*2);
  unsigned short* Ptlo   = (unsigned short*)take((size_t)16*65536*2);
  unsigned short* G2hi   = (unsigned short*)take((size_t)16*65536*2);
  unsigned short* G2lo   = (unsigned short*)take((size_t)16*65536*2);
  unsigned short* W1hi   = (unsigned short*)take((size_t)16*65536*2);
  unsigned short* W1lo   = (unsigned short*)take((size_t)16*65536*2);
  unsigned short* a1hi   = (unsigned short*)take((size_t)16*65536*2);
  unsigned short* a1lo   = (unsigned short*)take((size_t)16*65536*2);
  unsigned short* a2g    = (unsigned short*)take((size_t)16*65536*2);
  float*          ups    = (float*)take((size_t)1024*256*4);
  float*          u      = (float*)take((size_t)16*256*4);
  float*          wqu    = (float*)take((size_t)16*256*4);
  float*          wku    = (float*)take((size_t)16*256*4);
  float*          wtku   = (float*)take((size_t)16*256*4);
  float*          c1_g   = (float*)take((size_t)16*256*4);
  float*          ph1_g  = (float*)take((size_t)16*256*4);
  float*          b1eff  = (float*)take((size_t)16*256*4);
  float*          wtqh   = (float*)take((size_t)16*256*4);

  hipMemsetAsync(ph1_g, 0, (size_t)16*256*4, stream);

  k_wprep<<<dim3(1792), 256, 0, stream>>>(sq_w, sk_w, sv_w, tq_w, tk_w, tv_w,
                                          Whi, Wlo, WvThi, WvTlo);
  k_xprep2<<<dim3(1024), 256, 0, stream>>>(x, Xhi, Xlo, ups);
  k_vecfin<<<dim3(16), 256, 0, stream>>>(ups, u);
  k_vec1<<<dim3(16,3), 256, 0, stream>>>(sq_w, sq_b, sk_w, tk_w, u, wqu, wku, wtku);

  k_gram<false><<<dim3(2,2,128), 256, 0, stream>>>(Xhi, Xlo, Gp);
  k_gcomb<<<dim3(256,16), 256, 0, stream>>>(Gp, G1hi, G1lo);
  k_gram<true><<<dim3(2,2,128), 256, 0, stream>>>(Xhi, Xlo, Gp);
  k_gcomb<<<dim3(256,16), 256, 0, stream>>>(Gp, GShi, GSlo);

  // v2 conv (independent): v2T[bl][d][s] = Wtv X^T + btv
  k_vconv<<<dim3(2,32,16), 256, 0, stream>>>(Whi+5*65536, Xhi, tv_b, v2T);

  // S1: Pt1 = Wk x G1
  k_cgemm<0><<<dim3(2,2,16), 256, 0, stream>>>(
     Whi+1*65536, Wlo+1*65536, 0,  G1hi, G1lo, 65536,
     nullptr,0, nullptr,0, nullptr, nullptr, nullptr, Pthi, Ptlo);
  // S2: a1 = softmax(Wq x Pt1 + wqu*skb + sqb*wku), c1
  k_logit<0><<<dim3(2,1,16), 512, 0, stream>>>(
     Whi, Wlo, Pthi, Ptlo,
     wqu,256, sk_b,0, sq_b,0, wku,256,
     sv_b, nullptr, c1_g, a1hi, a1lo);
  // S4: W1 = I + gs*(a1 x WvT), h1 atomics
  k_cgemm<2><<<dim3(2,2,16), 256, 0, stream>>>(
     a1hi, a1lo, 65536,  WvThi, WvTlo, 0,
     nullptr,0, nullptr,0, s_g, u, ph1_g, W1hi, W1lo);
  // vec2: b1eff, wtqh
  k_vec2<<<dim3(16), 256, 0, stream>>>(ph1_g, c1_g, s_g, tq_w, tq_b, b1eff, wtqh);
  // S6: G2 = W1 x GS + b1eff*u^T
  k_cgemm<0><<<dim3(2,2,16), 256, 0, stream>>>(
     W1hi, W1lo, 65536,  GShi, GSlo, 65536,
     b1eff,256, u,256, nullptr, nullptr, nullptr, G2hi, G2lo);
  // S7: Pt2 = Wtk x G2
  k_cgemm<0><<<dim3(2,2,16), 256, 0, stream>>>(
     Whi+4*65536, Wlo+4*65536, 0,  G2hi, G2lo, 65536,
     nullptr,0, nullptr,0, nullptr, nullptr, nullptr, Pthi, Ptlo);
  // S8: a2g = tg * softmax(Wtq x Pt2 + wtqh*tkb + tqb*wtku)
  k_logit<1><<<dim3(2,1,16), 512, 0, stream>>>(
     Whi+3*65536, Wlo+3*65536, Pthi, Ptlo,
     wtqh,256, tk_b,0, tq_b,0, wtku,256,
     sv_b, t_g, nullptr, a2g, a2g);

  k_final<<<dim3(32,2,16), 256, 0, stream>>>(v2T, a2g, Xhi, Xlo, W1hi, W1lo, b1eff, (float*)d_out);
}